// Round 4
// baseline (2498.605 us; speedup 1.0000x reference)
//
#include <hip/hip_runtime.h>
#include <math.h>

// ---------------- problem constants ----------------
constexpr int SEQ = 1024;
constexpr int HID = 2048;
constexpr int DHEAD = 64;
constexpr int GUN = 4096;   // 2*I
constexpr int IDIM = 2048;
constexpr float EPSV = 1e-5f;
constexpr float ALPHAV = 1.702f;
constexpr float LIMITV = 7.0f;

__device__ __forceinline__ float4 ld4(const float* p) { return *(const float4*)p; }
__device__ __forceinline__ void st4(float* p, float4 v) { *(float4*)p = v; }

// ---------------- RMSNorm (note: reference MULTIPLIES by sqrt(var+eps)) ----------------
__global__ __launch_bounds__(256) void rmsnorm_kernel(const float* __restrict__ x,
                                                      const float* __restrict__ w,
                                                      float* __restrict__ out) {
  int t = blockIdx.x;
  const float* xr = x + (size_t)t * HID;
  int tid = threadIdx.x;
  float4 a0 = ld4(xr + tid * 4);
  float4 a1 = ld4(xr + 1024 + tid * 4);
  float ss = a0.x * a0.x + a0.y * a0.y + a0.z * a0.z + a0.w * a0.w +
             a1.x * a1.x + a1.y * a1.y + a1.z * a1.z + a1.w * a1.w;
#pragma unroll
  for (int m = 1; m < 64; m <<= 1) ss += __shfl_xor(ss, m);
  __shared__ float red[4];
  int wid = tid >> 6, lane = tid & 63;
  if (lane == 0) red[wid] = ss;
  __syncthreads();
  float tot = red[0] + red[1] + red[2] + red[3];
  float sc = sqrtf(tot * (1.0f / HID) + EPSV);
  float4 w0 = ld4(w + tid * 4), w1 = ld4(w + 1024 + tid * 4);
  float4 o0, o1;
  o0.x = w0.x * (a0.x * sc); o0.y = w0.y * (a0.y * sc);
  o0.z = w0.z * (a0.z * sc); o0.w = w0.w * (a0.w * sc);
  o1.x = w1.x * (a1.x * sc); o1.y = w1.y * (a1.y * sc);
  o1.z = w1.z * (a1.z * sc); o1.w = w1.w * (a1.w * sc);
  st4(out + (size_t)t * HID + tid * 4, o0);
  st4(out + (size_t)t * HID + 1024 + tid * 4, o1);
}

// ---------------- GEMM NT body: C[M,N] = A[M,K] @ B[N,K]^T (+bias)(+res) ----------------
// BM=BN=128, BK=16, 256 threads, 8x8 per-thread tile. Dims must be multiples of tile.
__device__ __forceinline__ void gemm_nt_body(const float* __restrict__ A,
                                             const float* __restrict__ B,
                                             const float* __restrict__ bias,
                                             const float* __restrict__ res,
                                             float* __restrict__ C, int N, int K) {
  __shared__ float As[16][132];
  __shared__ float Bs[16][132];
  int tid = threadIdx.x;
  int bn0 = blockIdx.x * 128, bm0 = blockIdx.y * 128;
  int tr = tid >> 4, tc = tid & 15;
  float acc[8][8];
#pragma unroll
  for (int i = 0; i < 8; i++)
#pragma unroll
    for (int j = 0; j < 8; j++) acc[i][j] = 0.f;
  int r0 = tid >> 2, kc = tid & 3;
  for (int k0 = 0; k0 < K; k0 += 16) {
#pragma unroll
    for (int i = 0; i < 2; ++i) {
      int row = r0 + i * 64;
      float4 av = ld4(&A[(size_t)(bm0 + row) * K + k0 + kc * 4]);
      As[kc * 4 + 0][row] = av.x; As[kc * 4 + 1][row] = av.y;
      As[kc * 4 + 2][row] = av.z; As[kc * 4 + 3][row] = av.w;
      float4 bv = ld4(&B[(size_t)(bn0 + row) * K + k0 + kc * 4]);
      Bs[kc * 4 + 0][row] = bv.x; Bs[kc * 4 + 1][row] = bv.y;
      Bs[kc * 4 + 2][row] = bv.z; Bs[kc * 4 + 3][row] = bv.w;
    }
    __syncthreads();
#pragma unroll
    for (int kk = 0; kk < 16; ++kk) {
      float a[8], b[8];
      *(float4*)&a[0] = ld4(&As[kk][tr * 8]);
      *(float4*)&a[4] = ld4(&As[kk][tr * 8 + 4]);
      *(float4*)&b[0] = ld4(&Bs[kk][tc * 4]);
      *(float4*)&b[4] = ld4(&Bs[kk][64 + tc * 4]);
#pragma unroll
      for (int i = 0; i < 8; i++)
#pragma unroll
        for (int j = 0; j < 8; j++) acc[i][j] += a[i] * b[j];
    }
    __syncthreads();
  }
#pragma unroll
  for (int i = 0; i < 8; ++i) {
    int gm = bm0 + tr * 8 + i;
#pragma unroll
    for (int half = 0; half < 2; ++half) {
      int gn = bn0 + half * 64 + tc * 4;
      float4 v;
      v.x = acc[i][half * 4 + 0]; v.y = acc[i][half * 4 + 1];
      v.z = acc[i][half * 4 + 2]; v.w = acc[i][half * 4 + 3];
      if (bias) {
        float4 bb = ld4(&bias[gn]);
        v.x += bb.x; v.y += bb.y; v.z += bb.z; v.w += bb.w;
      }
      if (res) {
        float4 rr = ld4(&res[(size_t)gm * N + gn]);
        v.x += rr.x; v.y += rr.y; v.z += rr.z; v.w += rr.w;
      }
      st4(&C[(size_t)gm * N + gn], v);
    }
  }
}

__global__ __launch_bounds__(256) void gemm_qkv_kernel(
    const float* __restrict__ A, const float* __restrict__ Wq,
    const float* __restrict__ Wk, const float* __restrict__ Wv,
    const float* __restrict__ bq, const float* __restrict__ bk,
    const float* __restrict__ bv, float* __restrict__ Oq, float* __restrict__ Ok,
    float* __restrict__ Ov) {
  const float* B; const float* bias; float* C;
  if (blockIdx.z == 0) { B = Wq; bias = bq; C = Oq; }
  else if (blockIdx.z == 1) { B = Wk; bias = bk; C = Ok; }
  else { B = Wv; bias = bv; C = Ov; }
  gemm_nt_body(A, B, bias, nullptr, C, HID, HID);
}

__global__ __launch_bounds__(256) void gemm_wo_kernel(const float* __restrict__ A,
                                                      const float* __restrict__ B,
                                                      const float* __restrict__ bias,
                                                      const float* __restrict__ res,
                                                      float* __restrict__ C) {
  gemm_nt_body(A, B, bias, res, C, HID, HID);
}

// ---------------- RoPE (in-place on q,k; layout (S, NH*D)) ----------------
__global__ __launch_bounds__(256) void rope_kernel(float* __restrict__ q,
                                                   float* __restrict__ k,
                                                   const float* __restrict__ cs,
                                                   const float* __restrict__ sn) {
  int idx = blockIdx.x * 256 + threadIdx.x;  // < 1024*1024
  int s = idx >> 10;
  int r = idx & 1023;
  int h = r >> 5;
  int i = r & 31;
  size_t base = (size_t)s * HID + h * DHEAD + i;
  float c = cs[s * 32 + i], ss = sn[s * 32 + i];
  float q1 = q[base], q2 = q[base + 32];
  q[base] = q1 * c - q2 * ss;
  q[base + 32] = q2 * c + q1 * ss;
  float k1 = k[base], k2 = k[base + 32];
  k[base] = k1 * c - k2 * ss;
  k[base + 32] = k2 * c + k1 * ss;
}

// ---------------- Flash attention with sink (64x64 tiles, 64KB LDS, swizzled) ----------------
__device__ __forceinline__ int idxA(int r, int c4) { return r * 64 + ((c4 ^ ((r >> 2) & 7)) << 2); }
__device__ __forceinline__ int idxB(int r, int c4) { return r * 64 + ((c4 ^ (r & 7)) << 2); }

__global__ __launch_bounds__(256) void attn_kernel(const float* __restrict__ Q,
                                                   const float* __restrict__ Kt,
                                                   const float* __restrict__ Vt,
                                                   const float* __restrict__ sinks,
                                                   float* __restrict__ O) {
  __shared__ float qs[64 * 64];
  __shared__ float ks[64 * 64];
  __shared__ float vs[64 * 64];
  __shared__ float ps[64 * 64];
  int h = blockIdx.y, qt = blockIdx.x;
  int q0 = qt * 64;
  int tid = threadIdx.x;
  int rg = tid >> 4, cg = tid & 15;
  int rr = rg * 4, cc = cg * 4, dd = cg * 4;

#pragma unroll
  for (int i = 0; i < 4; ++i) {
    int f = tid + i * 256;
    int row = f >> 4, c4 = f & 15;
    st4(&qs[idxB(row, c4)], ld4(&Q[(size_t)(q0 + row) * HID + h * DHEAD + c4 * 4]));
  }
  float snk = sinks[h];
  float m[4], l[4];
  float4 acc[4];
#pragma unroll
  for (int i = 0; i < 4; ++i) {
    m[i] = snk; l[i] = 1.0f;
    acc[i].x = acc[i].y = acc[i].z = acc[i].w = 0.f;
  }
  __syncthreads();

  for (int kt = 0; kt <= qt; ++kt) {
    int k0 = kt * 64;
#pragma unroll
    for (int i = 0; i < 4; ++i) {
      int f = tid + i * 256;
      int row = f >> 4, c4 = f & 15;
      st4(&ks[idxA(row, c4)], ld4(&Kt[(size_t)(k0 + row) * HID + h * DHEAD + c4 * 4]));
      st4(&vs[idxA(row, c4)], ld4(&Vt[(size_t)(k0 + row) * HID + h * DHEAD + c4 * 4]));
    }
    __syncthreads();

    float s[4][4];
#pragma unroll
    for (int i = 0; i < 4; ++i)
#pragma unroll
      for (int j = 0; j < 4; ++j) s[i][j] = 0.f;
#pragma unroll
    for (int c4 = 0; c4 < 16; ++c4) {
      float4 q4[4], k4[4];
#pragma unroll
      for (int i = 0; i < 4; ++i) q4[i] = ld4(&qs[idxB(rr + i, c4)]);
#pragma unroll
      for (int j = 0; j < 4; ++j) k4[j] = ld4(&ks[idxA(cc + j, c4)]);
#pragma unroll
      for (int i = 0; i < 4; ++i)
#pragma unroll
        for (int j = 0; j < 4; ++j)
          s[i][j] += q4[i].x * k4[j].x + q4[i].y * k4[j].y + q4[i].z * k4[j].z +
                     q4[i].w * k4[j].w;
    }
    bool diag = (kt == qt);
    float rowmax[4];
#pragma unroll
    for (int i = 0; i < 4; ++i) {
#pragma unroll
      for (int j = 0; j < 4; ++j) {
        s[i][j] *= 0.125f;
        if (diag && (cc + j > rr + i)) s[i][j] = -3.0e38f;
      }
      rowmax[i] = fmaxf(fmaxf(s[i][0], s[i][1]), fmaxf(s[i][2], s[i][3]));
    }
#pragma unroll
    for (int msk = 1; msk < 16; msk <<= 1)
#pragma unroll
      for (int i = 0; i < 4; ++i) rowmax[i] = fmaxf(rowmax[i], __shfl_xor(rowmax[i], msk));
    float psum[4];
#pragma unroll
    for (int i = 0; i < 4; ++i) {
      float mn = fmaxf(m[i], rowmax[i]);
      float sc = __expf(m[i] - mn);
      float4 p4;
      p4.x = __expf(s[i][0] - mn);
      p4.y = __expf(s[i][1] - mn);
      p4.z = __expf(s[i][2] - mn);
      p4.w = __expf(s[i][3] - mn);
      psum[i] = p4.x + p4.y + p4.z + p4.w;
      m[i] = mn;
      l[i] *= sc;
      acc[i].x *= sc; acc[i].y *= sc; acc[i].z *= sc; acc[i].w *= sc;
      st4(&ps[idxB(rr + i, cg)], p4);
    }
#pragma unroll
    for (int msk = 1; msk < 16; msk <<= 1)
#pragma unroll
      for (int i = 0; i < 4; ++i) psum[i] += __shfl_xor(psum[i], msk);
#pragma unroll
    for (int i = 0; i < 4; ++i) l[i] += psum[i];
    __syncthreads();

#pragma unroll
    for (int j4 = 0; j4 < 16; ++j4) {
      float4 p4[4], v4[4];
#pragma unroll
      for (int i = 0; i < 4; ++i) p4[i] = ld4(&ps[idxB(rr + i, j4)]);
#pragma unroll
      for (int jj = 0; jj < 4; ++jj) v4[jj] = ld4(&vs[idxA(j4 * 4 + jj, cg)]);
#pragma unroll
      for (int i = 0; i < 4; ++i) {
        acc[i].x += p4[i].x * v4[0].x + p4[i].y * v4[1].x + p4[i].z * v4[2].x + p4[i].w * v4[3].x;
        acc[i].y += p4[i].x * v4[0].y + p4[i].y * v4[1].y + p4[i].z * v4[2].y + p4[i].w * v4[3].y;
        acc[i].z += p4[i].x * v4[0].z + p4[i].y * v4[1].z + p4[i].z * v4[2].z + p4[i].w * v4[3].z;
        acc[i].w += p4[i].x * v4[0].w + p4[i].y * v4[1].w + p4[i].z * v4[2].w + p4[i].w * v4[3].w;
      }
    }
    __syncthreads();
  }
#pragma unroll
  for (int i = 0; i < 4; ++i) {
    float inv = 1.0f / l[i];
    float4 o;
    o.x = acc[i].x * inv; o.y = acc[i].y * inv;
    o.z = acc[i].z * inv; o.w = acc[i].w * inv;
    st4(&O[(size_t)(q0 + rr + i) * HID + h * DHEAD + dd], o);
  }
}

// ---------------- Router (top-2 + softmax over the two) ----------------
__global__ __launch_bounds__(64) void router_kernel(const float* __restrict__ t2,
                                                    const float* __restrict__ rw,
                                                    const float* __restrict__ rb,
                                                    int* __restrict__ cnt,
                                                    int* __restrict__ te,
                                                    float* __restrict__ tw) {
  int t = blockIdx.x;
  int lane = threadIdx.x;
  int e = lane >> 3, p = lane & 7;
  const float4* x4 = (const float4*)(t2 + (size_t)t * HID);
  const float4* w4 = (const float4*)(rw + (size_t)e * HID);
  float s = 0.f;
  for (int i = 0; i < 64; ++i) {
    float4 xv = x4[p + 8 * i];
    float4 wv = w4[p + 8 * i];
    s += xv.x * wv.x + xv.y * wv.y + xv.z * wv.z + xv.w * wv.w;
  }
  s += __shfl_xor(s, 1);
  s += __shfl_xor(s, 2);
  s += __shfl_xor(s, 4);
  float logit = s + rb[e];
  float lg[8];
#pragma unroll
  for (int e2 = 0; e2 < 8; ++e2) lg[e2] = __shfl(logit, e2 * 8);
  if (lane == 0) {
    int b0 = 0; float v0 = lg[0];
#pragma unroll
    for (int e2 = 1; e2 < 8; ++e2)
      if (lg[e2] > v0) { v0 = lg[e2]; b0 = e2; }
    int b1 = -1; float v1 = -3.0e38f;
#pragma unroll
    for (int e2 = 0; e2 < 8; ++e2)
      if (e2 != b0 && lg[e2] > v1) { v1 = lg[e2]; b1 = e2; }
    float e1 = __expf(v1 - v0);
    float z = 1.0f + e1;
    te[2 * t] = b0; te[2 * t + 1] = b1;
    tw[2 * t] = 1.0f / z; tw[2 * t + 1] = e1 / z;
    atomicAdd(&cnt[b0], 1);
    atomicAdd(&cnt[b1], 1);
  }
}

__global__ void zero_cnt_kernel(int* __restrict__ cnt) {
  if (threadIdx.x < 8) cnt[threadIdx.x] = 0;
}

__global__ void offsets_kernel(const int* __restrict__ cnt, int* __restrict__ offE,
                               int* __restrict__ fill) {
  if (threadIdx.x == 0) {
    int r = 0;
    for (int e = 0; e < 8; ++e) { offE[e] = r; fill[e] = r; r += cnt[e]; }
  }
}

__global__ __launch_bounds__(256) void scatter_kernel(const int* __restrict__ te,
                                                      int* __restrict__ fill,
                                                      int* __restrict__ tokbuf,
                                                      int* __restrict__ tokslot) {
  int t = blockIdx.x * 256 + threadIdx.x;
  if (t < SEQ) {
    for (int j = 0; j < 2; ++j) {
      int e = te[2 * t + j];
      int slot = atomicAdd(&fill[e], 1);
      tokbuf[slot] = t;
      tokslot[2 * t + j] = slot;
    }
  }
}

// ---------------- MoE gate_up GEMM (NN) + fused activation ----------------
__global__ __launch_bounds__(256) void gateup_kernel(
    const float* __restrict__ t2, const float* __restrict__ guw,
    const float* __restrict__ gub, const int* __restrict__ tokbuf,
    const int* __restrict__ cnt, const int* __restrict__ offE,
    float* __restrict__ act) {
  int e = blockIdx.z;
  int ce = cnt[e];
  int m0 = blockIdx.y * 128;
  if (m0 >= ce) return;
  int oe = offE[e];
  int n0 = blockIdx.x * 128;
  const float* B = guw + (size_t)e * HID * GUN;
  __shared__ float As[16][132];
  __shared__ float Bs[16][132];
  __shared__ int tokrow[128];
  int tid = threadIdx.x;
  if (tid < 128) tokrow[tid] = (m0 + tid < ce) ? tokbuf[oe + m0 + tid] : 0;
  __syncthreads();
  int tr = tid >> 4, tc = tid & 15;
  float acc[8][8];
#pragma unroll
  for (int i = 0; i < 8; i++)
#pragma unroll
    for (int j = 0; j < 8; j++) acc[i][j] = 0.f;
  int r0 = tid >> 2, kc = tid & 3;
  int brow = tid >> 5, bnc = tid & 31;
  for (int k0 = 0; k0 < HID; k0 += 16) {
#pragma unroll
    for (int i = 0; i < 2; ++i) {
      int row = r0 + i * 64;
      float4 av;
      if (m0 + row < ce)
        av = ld4(&t2[(size_t)tokrow[row] * HID + k0 + kc * 4]);
      else
        av.x = av.y = av.z = av.w = 0.f;
      As[kc * 4 + 0][row] = av.x; As[kc * 4 + 1][row] = av.y;
      As[kc * 4 + 2][row] = av.z; As[kc * 4 + 3][row] = av.w;
      int kr = brow + i * 8;
      st4(&Bs[kr][bnc * 4], ld4(&B[(size_t)(k0 + kr) * GUN + n0 + bnc * 4]));
    }
    __syncthreads();
#pragma unroll
    for (int kk = 0; kk < 16; ++kk) {
      float a[8], b[8];
      *(float4*)&a[0] = ld4(&As[kk][tr * 8]);
      *(float4*)&a[4] = ld4(&As[kk][tr * 8 + 4]);
      *(float4*)&b[0] = ld4(&Bs[kk][tc * 4]);
      *(float4*)&b[4] = ld4(&Bs[kk][64 + tc * 4]);
#pragma unroll
      for (int i = 0; i < 8; i++)
#pragma unroll
        for (int j = 0; j < 8; j++) acc[i][j] += a[i] * b[j];
    }
    __syncthreads();
  }
  const float* gb = gub + (size_t)e * GUN;
#pragma unroll
  for (int i = 0; i < 8; ++i) {
    int mm = m0 + tr * 8 + i;
    if (mm >= ce) continue;
    size_t arow = (size_t)(oe + mm) * IDIM;
#pragma unroll
    for (int half = 0; half < 2; ++half) {
      int gn = n0 + half * 64 + tc * 4;  // even gu col base
      float g0 = acc[i][half * 4 + 0] + gb[gn + 0];
      float u0 = acc[i][half * 4 + 1] + gb[gn + 1];
      float g1 = acc[i][half * 4 + 2] + gb[gn + 2];
      float u1 = acc[i][half * 4 + 3] + gb[gn + 3];
      g0 = fminf(g0, LIMITV);
      g1 = fminf(g1, LIMITV);
      u0 = fminf(fmaxf(u0, -LIMITV), LIMITV);
      u1 = fminf(fmaxf(u1, -LIMITV), LIMITV);
      float a0 = (u0 + 1.0f) * (g0 / (1.0f + __expf(-ALPHAV * g0)));
      float a1 = (u1 + 1.0f) * (g1 / (1.0f + __expf(-ALPHAV * g1)));
      act[arow + (gn >> 1)] = a0;
      act[arow + (gn >> 1) + 1] = a1;
    }
  }
}

// ---------------- MoE down GEMM (NN) ----------------
__global__ __launch_bounds__(256) void down_kernel(const float* __restrict__ act,
                                                   const float* __restrict__ dw,
                                                   const float* __restrict__ db,
                                                   const int* __restrict__ cnt,
                                                   const int* __restrict__ offE,
                                                   float* __restrict__ dout) {
  int e = blockIdx.z;
  int ce = cnt[e];
  int m0 = blockIdx.y * 128;
  if (m0 >= ce) return;
  int oe = offE[e];
  int n0 = blockIdx.x * 128;
  const float* B = dw + (size_t)e * IDIM * HID;
  __shared__ float As[16][132];
  __shared__ float Bs[16][132];
  int tid = threadIdx.x;
  int tr = tid >> 4, tc = tid & 15;
  float acc[8][8];
#pragma unroll
  for (int i = 0; i < 8; i++)
#pragma unroll
    for (int j = 0; j < 8; j++) acc[i][j] = 0.f;
  int r0 = tid >> 2, kc = tid & 3;
  int brow = tid >> 5, bnc = tid & 31;
  for (int k0 = 0; k0 < IDIM; k0 += 16) {
#pragma unroll
    for (int i = 0; i < 2; ++i) {
      int row = r0 + i * 64;
      float4 av;
      if (m0 + row < ce)
        av = ld4(&act[(size_t)(oe + m0 + row) * IDIM + k0 + kc * 4]);
      else
        av.x = av.y = av.z = av.w = 0.f;
      As[kc * 4 + 0][row] = av.x; As[kc * 4 + 1][row] = av.y;
      As[kc * 4 + 2][row] = av.z; As[kc * 4 + 3][row] = av.w;
      int kr = brow + i * 8;
      st4(&Bs[kr][bnc * 4], ld4(&B[(size_t)(k0 + kr) * HID + n0 + bnc * 4]));
    }
    __syncthreads();
#pragma unroll
    for (int kk = 0; kk < 16; ++kk) {
      float a[8], b[8];
      *(float4*)&a[0] = ld4(&As[kk][tr * 8]);
      *(float4*)&a[4] = ld4(&As[kk][tr * 8 + 4]);
      *(float4*)&b[0] = ld4(&Bs[kk][tc * 4]);
      *(float4*)&b[4] = ld4(&Bs[kk][64 + tc * 4]);
#pragma unroll
      for (int i = 0; i < 8; i++)
#pragma unroll
        for (int j = 0; j < 8; j++) acc[i][j] += a[i] * b[j];
    }
    __syncthreads();
  }
  const float* dbb = db + (size_t)e * HID;
#pragma unroll
  for (int i = 0; i < 8; ++i) {
    int mm = m0 + tr * 8 + i;
    if (mm >= ce) continue;
    size_t orow = (size_t)(oe + mm) * HID;
#pragma unroll
    for (int half = 0; half < 2; ++half) {
      int gn = n0 + half * 64 + tc * 4;
      float4 bb = ld4(&dbb[gn]);
      float4 v;
      v.x = acc[i][half * 4 + 0] + bb.x;
      v.y = acc[i][half * 4 + 1] + bb.y;
      v.z = acc[i][half * 4 + 2] + bb.z;
      v.w = acc[i][half * 4 + 3] + bb.w;
      st4(&dout[orow + gn], v);
    }
  }
}

// ---------------- final combine: out = x2 + w0*down[s0] + w1*down[s1] ----------------
__global__ __launch_bounds__(256) void combine_kernel(const float* __restrict__ x2,
                                                      const float* __restrict__ dout,
                                                      const int* __restrict__ tokslot,
                                                      const float* __restrict__ tw,
                                                      float* __restrict__ out) {
  int idx = blockIdx.x * 256 + threadIdx.x;  // < 1024*512
  int t = idx >> 9, c = idx & 511;
  int s0 = tokslot[2 * t], s1 = tokslot[2 * t + 1];
  float w0 = tw[2 * t], w1 = tw[2 * t + 1];
  float4 r = ld4(x2 + (size_t)t * HID + c * 4);
  float4 a = ld4(dout + (size_t)s0 * HID + c * 4);
  float4 b = ld4(dout + (size_t)s1 * HID + c * 4);
  float4 o;
  o.x = r.x + w0 * a.x + w1 * b.x;
  o.y = r.y + w0 * a.y + w1 * b.y;
  o.z = r.z + w0 * a.z + w1 * b.z;
  o.w = r.w + w0 * a.w + w1 * b.w;
  st4(out + (size_t)t * HID + c * 4, o);
}

// ---------------- launch ----------------
extern "C" void kernel_launch(void* const* d_in, const int* in_sizes, int n_in,
                              void* d_out, int out_size, void* d_ws, size_t ws_size,
                              hipStream_t stream) {
  (void)in_sizes; (void)n_in; (void)out_size; (void)ws_size;
  const float* x      = (const float*)d_in[0];
  // d_in[1] = attention_mask (unused; reproduced analytically — exact in fp32)
  const float* cosT   = (const float*)d_in[2];
  const float* sinT   = (const float*)d_in[3];
  const float* wq     = (const float*)d_in[4];
  const float* bq     = (const float*)d_in[5];
  const float* wk     = (const float*)d_in[6];
  const float* bk     = (const float*)d_in[7];
  const float* wv     = (const float*)d_in[8];
  const float* bv     = (const float*)d_in[9];
  const float* wo     = (const float*)d_in[10];
  const float* bo     = (const float*)d_in[11];
  const float* sinks  = (const float*)d_in[12];
  const float* ln1w   = (const float*)d_in[13];
  const float* ln2w   = (const float*)d_in[14];
  const float* rw     = (const float*)d_in[15];
  const float* rb     = (const float*)d_in[16];
  const float* guw    = (const float*)d_in[17];
  const float* gub    = (const float*)d_in[18];
  const float* dww    = (const float*)d_in[19];
  const float* dwb    = (const float*)d_in[20];
  float* out = (float*)d_out;

  float* ws = (float*)d_ws;
  const size_t T2M = 2097152;  // 2M floats = one (1024,2048) tensor
  float* h    = ws;             // [0, 2M)   — dead after QKV
  float* q    = ws + 1 * T2M;   // [2M, 4M)
  float* k    = ws + 2 * T2M;   // [4M, 6M)
  float* v    = ws + 3 * T2M;   // [6M, 8M)
  float* attn = ws;             // alias h   — written after h's last read
  float* x2   = ws + 4 * T2M;   // [8M, 10M)
  float* t2   = ws + 5 * T2M;   // [10M, 12M)
  float* actb = ws + 1 * T2M;   // [2M, 6M)  — aliases q,k (dead after attention)
  float* down = ws + 6 * T2M;   // [12M, 16M)
  int* misc = (int*)(ws + 3 * T2M);  // inside v region — written only after attention
  int* cnt     = misc;
  int* offE    = misc + 8;
  int* fill    = misc + 16;
  int* te      = misc + 32;
  int* tokslot = misc + 32 + 2048;
  int* tokbuf  = misc + 32 + 4096;
  float* tw    = (float*)(misc + 32 + 6144);

  rmsnorm_kernel<<<SEQ, 256, 0, stream>>>(x, ln1w, h);
  gemm_qkv_kernel<<<dim3(16, 8, 3), 256, 0, stream>>>(h, wq, wk, wv, bq, bk, bv, q, k, v);
  rope_kernel<<<4096, 256, 0, stream>>>(q, k, cosT, sinT);
  attn_kernel<<<dim3(16, 32), 256, 0, stream>>>(q, k, v, sinks, attn);
  gemm_wo_kernel<<<dim3(16, 8), 256, 0, stream>>>(attn, wo, bo, x, x2);
  rmsnorm_kernel<<<SEQ, 256, 0, stream>>>(x2, ln2w, t2);
  zero_cnt_kernel<<<1, 64, 0, stream>>>(cnt);
  router_kernel<<<SEQ, 64, 0, stream>>>(t2, rw, rb, cnt, te, tw);
  offsets_kernel<<<1, 64, 0, stream>>>(cnt, offE, fill);
  scatter_kernel<<<4, 256, 0, stream>>>(te, fill, tokbuf, tokslot);
  gateup_kernel<<<dim3(32, 8, 8), 256, 0, stream>>>(t2, guw, gub, tokbuf, cnt, offE, actb);
  down_kernel<<<dim3(16, 8, 8), 256, 0, stream>>>(actb, dww, dwb, cnt, offE, down);
  combine_kernel<<<2048, 256, 0, stream>>>(x2, down, tokslot, tw, out);
}

// Round 5
// 1256.611 us; speedup vs baseline: 1.9884x; 1.9884x over previous
//
#include <hip/hip_runtime.h>
#include <math.h>

// ---------------- problem constants ----------------
constexpr int SEQ = 1024;
constexpr int HID = 2048;
constexpr int DHEAD = 64;
constexpr int GUN = 4096;   // 2*I
constexpr int IDIM = 2048;
constexpr float EPSV = 1e-5f;
constexpr float ALPHAV = 1.702f;
constexpr float LIMITV = 7.0f;

typedef float f32x4 __attribute__((ext_vector_type(4)));
typedef float f32x16 __attribute__((ext_vector_type(16)));
typedef __bf16 bf16x8 __attribute__((ext_vector_type(8)));
typedef __bf16 bf16x4 __attribute__((ext_vector_type(4)));

__device__ __forceinline__ float4 ld4(const float* p) { return *(const float4*)p; }
__device__ __forceinline__ void st4(float* p, float4 v) { *(float4*)p = v; }
__device__ __forceinline__ f32x4 ld4v(const float* p) { return *(const f32x4*)p; }
__device__ __forceinline__ f32x4 zero4() {
  f32x4 v; v[0] = 0.f; v[1] = 0.f; v[2] = 0.f; v[3] = 0.f; return v;
}

// ================= bf16 MFMA GEMM core =================
// C[128,128] tile = A[128,K] x B(K,128); 256 threads, 4 waves in 2x2 grid,
// per-wave 64x64 via 2x2 frags of v_mfma_f32_32x32x16_bf16.
// BNN=0: B is [N][K] row-major (NT, weight @ W^T).  BNN=1: B is [K][N] (NN).
// A/B staged to LDS as bf16 [row][k] (row=m or n), 64B rows, 16B-granule XOR
// swizzle: byte ^= ((row>>3)&3)<<4  (write and read sides identical).
// f32->bf16 conversion fused into staging (RNE via compiler __bf16 cast).
template <int BNN>
__device__ __forceinline__ void gemm_core(const float* pa0, const float* pa1,
                                          const float* pb0, const float* pb1,
                                          const float* Bnn, int ldbn, int K,
                                          f32x16 acc[2][2]) {
  __shared__ __align__(16) unsigned char AsB[8192];
  __shared__ __align__(16) unsigned char BsB[8192];
  const int tid = threadIdx.x;
  const int lane = tid & 63, l31 = lane & 31, lh = lane >> 5;
  const int wid = tid >> 6;
  const int wm = (wid & 1) << 6, wn = (wid >> 1) << 6;
  const int arow = tid >> 2, ag = tid & 3;                 // staging: row, 16B granule
  const int aswz0 = ((arow >> 3) & 3) << 4;
  const int aswz1 = (((arow + 64) >> 3) & 3) << 4;
  const int n4 = (tid & 31) << 2, kq = (tid >> 5) << 2;    // NN staging micro-tile
  const int bswz = ((n4 >> 3) & 3) << 4;                   // same for n4..n4+3

  for (int k0 = 0; k0 < K; k0 += 32) {
    // ---- stage A rows (arow, arow+64): 8 f32 -> 8 bf16 -> one b128 write
    {
      f32x4 v0, v1;
      if (pa0) { v0 = ld4v(pa0 + k0); v1 = ld4v(pa0 + k0 + 4); }
      else { v0 = zero4(); v1 = zero4(); }
      bf16x8 w;
      w[0] = (__bf16)v0[0]; w[1] = (__bf16)v0[1]; w[2] = (__bf16)v0[2]; w[3] = (__bf16)v0[3];
      w[4] = (__bf16)v1[0]; w[5] = (__bf16)v1[1]; w[6] = (__bf16)v1[2]; w[7] = (__bf16)v1[3];
      *(bf16x8*)(AsB + arow * 64 + ((ag << 4) ^ aswz0)) = w;
      if (pa1) { v0 = ld4v(pa1 + k0); v1 = ld4v(pa1 + k0 + 4); }
      else { v0 = zero4(); v1 = zero4(); }
      w[0] = (__bf16)v0[0]; w[1] = (__bf16)v0[1]; w[2] = (__bf16)v0[2]; w[3] = (__bf16)v0[3];
      w[4] = (__bf16)v1[0]; w[5] = (__bf16)v1[1]; w[6] = (__bf16)v1[2]; w[7] = (__bf16)v1[3];
      *(bf16x8*)(AsB + (arow + 64) * 64 + ((ag << 4) ^ aswz1)) = w;
    }
    // ---- stage B
    if constexpr (BNN == 0) {
      f32x4 v0 = ld4v(pb0 + k0), v1 = ld4v(pb0 + k0 + 4);
      bf16x8 w;
      w[0] = (__bf16)v0[0]; w[1] = (__bf16)v0[1]; w[2] = (__bf16)v0[2]; w[3] = (__bf16)v0[3];
      w[4] = (__bf16)v1[0]; w[5] = (__bf16)v1[1]; w[6] = (__bf16)v1[2]; w[7] = (__bf16)v1[3];
      *(bf16x8*)(BsB + arow * 64 + ((ag << 4) ^ aswz0)) = w;
      v0 = ld4v(pb1 + k0); v1 = ld4v(pb1 + k0 + 4);
      w[0] = (__bf16)v0[0]; w[1] = (__bf16)v0[1]; w[2] = (__bf16)v0[2]; w[3] = (__bf16)v0[3];
      w[4] = (__bf16)v1[0]; w[5] = (__bf16)v1[1]; w[6] = (__bf16)v1[2]; w[7] = (__bf16)v1[3];
      *(bf16x8*)(BsB + (arow + 64) * 64 + ((ag << 4) ^ aswz1)) = w;
    } else {
      // B[K][N]: transpose 4k x 4n micro-tile into Bs[n][k]
      f32x4 bv0 = ld4v(Bnn + (size_t)(k0 + kq + 0) * ldbn + n4);
      f32x4 bv1 = ld4v(Bnn + (size_t)(k0 + kq + 1) * ldbn + n4);
      f32x4 bv2 = ld4v(Bnn + (size_t)(k0 + kq + 2) * ldbn + n4);
      f32x4 bv3 = ld4v(Bnn + (size_t)(k0 + kq + 3) * ldbn + n4);
#pragma unroll
      for (int nn = 0; nn < 4; ++nn) {
        bf16x4 w;
        w[0] = (__bf16)bv0[nn]; w[1] = (__bf16)bv1[nn];
        w[2] = (__bf16)bv2[nn]; w[3] = (__bf16)bv3[nn];
        *(bf16x4*)(BsB + (n4 + nn) * 64 + ((kq << 1) ^ bswz)) = w;
      }
    }
    __syncthreads();
#pragma unroll
    for (int ks = 0; ks < 2; ++ks) {
      const int b0 = (ks << 5) + (lh << 4);  // byte col of 8 bf16 (k = ks*16 + lh*8 ..+8)
      bf16x8 af[2], bfr[2];
#pragma unroll
      for (int i = 0; i < 2; ++i) {
        const int ra = wm + (i << 5) + l31;
        af[i] = *(const bf16x8*)(AsB + ra * 64 + (b0 ^ (((ra >> 3) & 3) << 4)));
        const int rb = wn + (i << 5) + l31;
        bfr[i] = *(const bf16x8*)(BsB + rb * 64 + (b0 ^ (((rb >> 3) & 3) << 4)));
      }
#pragma unroll
      for (int i = 0; i < 2; ++i)
#pragma unroll
        for (int j = 0; j < 2; ++j)
          acc[i][j] = __builtin_amdgcn_mfma_f32_32x32x16_bf16(af[i], bfr[j], acc[i][j], 0, 0, 0);
    }
    __syncthreads();
  }
}

__device__ __forceinline__ void zero_acc(f32x16 acc[2][2]) {
#pragma unroll
  for (int i = 0; i < 2; ++i)
#pragma unroll
    for (int j = 0; j < 2; ++j)
#pragma unroll
      for (int r = 0; r < 16; ++r) acc[i][j][r] = 0.f;
}

// C/D frag mapping (HW-verified m74/m101): col = lane&31, row = (r&3)+8*(r>>2)+4*(lane>>5)
#define CROW(r, lh) (((r) & 3) + (((r) >> 2) << 3) + ((lh) << 2))

// ---------------- QKV: C = A @ W^T + b, one of q/k/v per blockIdx.z ----------------
__global__ __launch_bounds__(256) void qkv_bf16_kernel(
    const float* __restrict__ A, const float* __restrict__ Wq,
    const float* __restrict__ Wk, const float* __restrict__ Wv,
    const float* __restrict__ bq, const float* __restrict__ bk,
    const float* __restrict__ bv, float* __restrict__ Oq,
    float* __restrict__ Ok, float* __restrict__ Ov) {
  const float* B; const float* bias; float* C;
  if (blockIdx.z == 0) { B = Wq; bias = bq; C = Oq; }
  else if (blockIdx.z == 1) { B = Wk; bias = bk; C = Ok; }
  else { B = Wv; bias = bv; C = Ov; }
  const int tid = threadIdx.x;
  const int bn0 = blockIdx.x * 128, bm0 = blockIdx.y * 128;
  const int arow = tid >> 2, ag = tid & 3;
  const float* pa0 = A + (size_t)(bm0 + arow) * HID + ag * 8;
  const float* pa1 = pa0 + (size_t)64 * HID;
  const float* pb0 = B + (size_t)(bn0 + arow) * HID + ag * 8;
  const float* pb1 = pb0 + (size_t)64 * HID;
  f32x16 acc[2][2];
  zero_acc(acc);
  gemm_core<0>(pa0, pa1, pb0, pb1, nullptr, 0, HID, acc);
  const int lane = tid & 63, l31 = lane & 31, lh = lane >> 5;
  const int wid = tid >> 6;
  const int wm = (wid & 1) << 6, wn = (wid >> 1) << 6;
#pragma unroll
  for (int j = 0; j < 2; ++j) {
    const int col = bn0 + wn + (j << 5) + l31;
    const float bcol = bias[col];
#pragma unroll
    for (int i = 0; i < 2; ++i)
#pragma unroll
      for (int r = 0; r < 16; ++r) {
        const int row = bm0 + wm + (i << 5) + CROW(r, lh);
        C[(size_t)row * HID + col] = acc[i][j][r] + bcol;
      }
  }
}

// ---------------- WO: C = A @ W^T + b + res ----------------
__global__ __launch_bounds__(256) void wo_bf16_kernel(
    const float* __restrict__ A, const float* __restrict__ B,
    const float* __restrict__ bias, const float* __restrict__ res,
    float* __restrict__ C) {
  const int tid = threadIdx.x;
  const int bn0 = blockIdx.x * 128, bm0 = blockIdx.y * 128;
  const int arow = tid >> 2, ag = tid & 3;
  const float* pa0 = A + (size_t)(bm0 + arow) * HID + ag * 8;
  const float* pa1 = pa0 + (size_t)64 * HID;
  const float* pb0 = B + (size_t)(bn0 + arow) * HID + ag * 8;
  const float* pb1 = pb0 + (size_t)64 * HID;
  f32x16 acc[2][2];
  zero_acc(acc);
  gemm_core<0>(pa0, pa1, pb0, pb1, nullptr, 0, HID, acc);
  const int lane = tid & 63, l31 = lane & 31, lh = lane >> 5;
  const int wid = tid >> 6;
  const int wm = (wid & 1) << 6, wn = (wid >> 1) << 6;
#pragma unroll
  for (int j = 0; j < 2; ++j) {
    const int col = bn0 + wn + (j << 5) + l31;
    const float bcol = bias[col];
#pragma unroll
    for (int i = 0; i < 2; ++i)
#pragma unroll
      for (int r = 0; r < 16; ++r) {
        const int row = bm0 + wm + (i << 5) + CROW(r, lh);
        C[(size_t)row * HID + col] = acc[i][j][r] + bcol + res[(size_t)row * HID + col];
      }
  }
}

// ---------------- MoE gate_up: act = f(compact(t2) @ guw[e] + gub[e]) ----------------
__global__ __launch_bounds__(256) void gateup_bf16_kernel(
    const float* __restrict__ t2, const float* __restrict__ guw,
    const float* __restrict__ gub, const int* __restrict__ tokbuf,
    const int* __restrict__ cnt, const int* __restrict__ offE,
    float* __restrict__ act) {
  const int e = blockIdx.z;
  const int ce = cnt[e];
  const int m0 = blockIdx.y * 128;
  if (m0 >= ce) return;
  const int oe = offE[e];
  const int bn0 = blockIdx.x * 128;
  const int tid = threadIdx.x;
  const int arow = tid >> 2, ag = tid & 3;
  const int r0 = m0 + arow, r1 = r0 + 64;
  const float* pa0 = (r0 < ce) ? t2 + (size_t)tokbuf[oe + r0] * HID + ag * 8 : nullptr;
  const float* pa1 = (r1 < ce) ? t2 + (size_t)tokbuf[oe + r1] * HID + ag * 8 : nullptr;
  const float* Bnn = guw + (size_t)e * HID * GUN + bn0;
  f32x16 acc[2][2];
  zero_acc(acc);
  gemm_core<1>(pa0, pa1, nullptr, nullptr, Bnn, GUN, HID, acc);
  const float* gb = gub + (size_t)e * GUN;
  const int lane = tid & 63, l31 = lane & 31, lh = lane >> 5;
  const int wid = tid >> 6;
  const int wm = (wid & 1) << 6, wn = (wid >> 1) << 6;
#pragma unroll
  for (int j = 0; j < 2; ++j) {
    const int gcol = bn0 + wn + (j << 5) + l31;  // gu-space col; even=gate, odd=up
    const float bcol = gb[gcol];
#pragma unroll
    for (int i = 0; i < 2; ++i)
#pragma unroll
      for (int r = 0; r < 16; ++r) {
        const int mrow = m0 + wm + (i << 5) + CROW(r, lh);
        const float v = acc[i][j][r] + bcol;
        const float other = __shfl_xor(v, 1);  // partner col's value
        if (!(l31 & 1) && mrow < ce) {         // even lane holds gate, partner holds up
          float g = fminf(v, LIMITV);
          float u = fminf(fmaxf(other, -LIMITV), LIMITV);
          float a = (u + 1.0f) * (g / (1.0f + __expf(-ALPHAV * g)));
          act[(size_t)(oe + mrow) * IDIM + (gcol >> 1)] = a;
        }
      }
  }
}

// ---------------- MoE down: dout = act @ dw[e] + db[e] ----------------
__global__ __launch_bounds__(256) void down_bf16_kernel(
    const float* __restrict__ act, const float* __restrict__ dw,
    const float* __restrict__ db, const int* __restrict__ cnt,
    const int* __restrict__ offE, float* __restrict__ dout) {
  const int e = blockIdx.z;
  const int ce = cnt[e];
  const int m0 = blockIdx.y * 128;
  if (m0 >= ce) return;
  const int oe = offE[e];
  const int bn0 = blockIdx.x * 128;
  const int tid = threadIdx.x;
  const int arow = tid >> 2, ag = tid & 3;
  const int r0 = m0 + arow, r1 = r0 + 64;
  const float* pa0 = (r0 < ce) ? act + (size_t)(oe + r0) * IDIM + ag * 8 : nullptr;
  const float* pa1 = (r1 < ce) ? act + (size_t)(oe + r1) * IDIM + ag * 8 : nullptr;
  const float* Bnn = dw + (size_t)e * IDIM * HID + bn0;
  f32x16 acc[2][2];
  zero_acc(acc);
  gemm_core<1>(pa0, pa1, nullptr, nullptr, Bnn, HID, IDIM, acc);
  const float* dbb = db + (size_t)e * HID;
  const int lane = tid & 63, l31 = lane & 31, lh = lane >> 5;
  const int wid = tid >> 6;
  const int wm = (wid & 1) << 6, wn = (wid >> 1) << 6;
#pragma unroll
  for (int j = 0; j < 2; ++j) {
    const int col = bn0 + wn + (j << 5) + l31;
    const float bcol = dbb[col];
#pragma unroll
    for (int i = 0; i < 2; ++i)
#pragma unroll
      for (int r = 0; r < 16; ++r) {
        const int mrow = m0 + wm + (i << 5) + CROW(r, lh);
        if (mrow < ce) dout[(size_t)(oe + mrow) * HID + col] = acc[i][j][r] + bcol;
      }
  }
}

// ---------------- RMSNorm (reference MULTIPLIES by sqrt(var+eps)) ----------------
__global__ __launch_bounds__(256) void rmsnorm_kernel(const float* __restrict__ x,
                                                      const float* __restrict__ w,
                                                      float* __restrict__ out) {
  int t = blockIdx.x;
  const float* xr = x + (size_t)t * HID;
  int tid = threadIdx.x;
  float4 a0 = ld4(xr + tid * 4);
  float4 a1 = ld4(xr + 1024 + tid * 4);
  float ss = a0.x * a0.x + a0.y * a0.y + a0.z * a0.z + a0.w * a0.w +
             a1.x * a1.x + a1.y * a1.y + a1.z * a1.z + a1.w * a1.w;
#pragma unroll
  for (int m = 1; m < 64; m <<= 1) ss += __shfl_xor(ss, m);
  __shared__ float red[4];
  int wid = tid >> 6, lane = tid & 63;
  if (lane == 0) red[wid] = ss;
  __syncthreads();
  float tot = red[0] + red[1] + red[2] + red[3];
  float sc = sqrtf(tot * (1.0f / HID) + EPSV);
  float4 w0 = ld4(w + tid * 4), w1 = ld4(w + 1024 + tid * 4);
  float4 o0, o1;
  o0.x = w0.x * (a0.x * sc); o0.y = w0.y * (a0.y * sc);
  o0.z = w0.z * (a0.z * sc); o0.w = w0.w * (a0.w * sc);
  o1.x = w1.x * (a1.x * sc); o1.y = w1.y * (a1.y * sc);
  o1.z = w1.z * (a1.z * sc); o1.w = w1.w * (a1.w * sc);
  st4(out + (size_t)t * HID + tid * 4, o0);
  st4(out + (size_t)t * HID + 1024 + tid * 4, o1);
}

// ---------------- RoPE (in-place on q,k) ----------------
__global__ __launch_bounds__(256) void rope_kernel(float* __restrict__ q,
                                                   float* __restrict__ k,
                                                   const float* __restrict__ cs,
                                                   const float* __restrict__ sn) {
  int idx = blockIdx.x * 256 + threadIdx.x;
  int s = idx >> 10;
  int r = idx & 1023;
  int h = r >> 5;
  int i = r & 31;
  size_t base = (size_t)s * HID + h * DHEAD + i;
  float c = cs[s * 32 + i], ss = sn[s * 32 + i];
  float q1 = q[base], q2 = q[base + 32];
  q[base] = q1 * c - q2 * ss;
  q[base + 32] = q2 * c + q1 * ss;
  float k1 = k[base], k2 = k[base + 32];
  k[base] = k1 * c - k2 * ss;
  k[base + 32] = k2 * c + k1 * ss;
}

// ---------------- Flash attention with sink (fp32, unchanged) ----------------
__device__ __forceinline__ int idxA(int r, int c4) { return r * 64 + ((c4 ^ ((r >> 2) & 7)) << 2); }
__device__ __forceinline__ int idxB(int r, int c4) { return r * 64 + ((c4 ^ (r & 7)) << 2); }

__global__ __launch_bounds__(256) void attn_kernel(const float* __restrict__ Q,
                                                   const float* __restrict__ Kt,
                                                   const float* __restrict__ Vt,
                                                   const float* __restrict__ sinks,
                                                   float* __restrict__ O) {
  __shared__ float qs[64 * 64];
  __shared__ float ks[64 * 64];
  __shared__ float vs[64 * 64];
  __shared__ float ps[64 * 64];
  int h = blockIdx.y, qt = blockIdx.x;
  int q0 = qt * 64;
  int tid = threadIdx.x;
  int rg = tid >> 4, cg = tid & 15;
  int rr = rg * 4, cc = cg * 4, dd = cg * 4;

#pragma unroll
  for (int i = 0; i < 4; ++i) {
    int f = tid + i * 256;
    int row = f >> 4, c4 = f & 15;
    st4(&qs[idxB(row, c4)], ld4(&Q[(size_t)(q0 + row) * HID + h * DHEAD + c4 * 4]));
  }
  float snk = sinks[h];
  float m[4], l[4];
  float4 acc[4];
#pragma unroll
  for (int i = 0; i < 4; ++i) {
    m[i] = snk; l[i] = 1.0f;
    acc[i].x = acc[i].y = acc[i].z = acc[i].w = 0.f;
  }
  __syncthreads();

  for (int kt = 0; kt <= qt; ++kt) {
    int k0 = kt * 64;
#pragma unroll
    for (int i = 0; i < 4; ++i) {
      int f = tid + i * 256;
      int row = f >> 4, c4 = f & 15;
      st4(&ks[idxA(row, c4)], ld4(&Kt[(size_t)(k0 + row) * HID + h * DHEAD + c4 * 4]));
      st4(&vs[idxA(row, c4)], ld4(&Vt[(size_t)(k0 + row) * HID + h * DHEAD + c4 * 4]));
    }
    __syncthreads();

    float s[4][4];
#pragma unroll
    for (int i = 0; i < 4; ++i)
#pragma unroll
      for (int j = 0; j < 4; ++j) s[i][j] = 0.f;
#pragma unroll
    for (int c4 = 0; c4 < 16; ++c4) {
      float4 q4[4], k4[4];
#pragma unroll
      for (int i = 0; i < 4; ++i) q4[i] = ld4(&qs[idxB(rr + i, c4)]);
#pragma unroll
      for (int j = 0; j < 4; ++j) k4[j] = ld4(&ks[idxA(cc + j, c4)]);
#pragma unroll
      for (int i = 0; i < 4; ++i)
#pragma unroll
        for (int j = 0; j < 4; ++j)
          s[i][j] += q4[i].x * k4[j].x + q4[i].y * k4[j].y + q4[i].z * k4[j].z +
                     q4[i].w * k4[j].w;
    }
    bool diag = (kt == qt);
    float rowmax[4];
#pragma unroll
    for (int i = 0; i < 4; ++i) {
#pragma unroll
      for (int j = 0; j < 4; ++j) {
        s[i][j] *= 0.125f;
        if (diag && (cc + j > rr + i)) s[i][j] = -3.0e38f;
      }
      rowmax[i] = fmaxf(fmaxf(s[i][0], s[i][1]), fmaxf(s[i][2], s[i][3]));
    }
#pragma unroll
    for (int msk = 1; msk < 16; msk <<= 1)
#pragma unroll
      for (int i = 0; i < 4; ++i) rowmax[i] = fmaxf(rowmax[i], __shfl_xor(rowmax[i], msk));
    float psum[4];
#pragma unroll
    for (int i = 0; i < 4; ++i) {
      float mn = fmaxf(m[i], rowmax[i]);
      float sc = __expf(m[i] - mn);
      float4 p4;
      p4.x = __expf(s[i][0] - mn);
      p4.y = __expf(s[i][1] - mn);
      p4.z = __expf(s[i][2] - mn);
      p4.w = __expf(s[i][3] - mn);
      psum[i] = p4.x + p4.y + p4.z + p4.w;
      m[i] = mn;
      l[i] *= sc;
      acc[i].x *= sc; acc[i].y *= sc; acc[i].z *= sc; acc[i].w *= sc;
      st4(&ps[idxB(rr + i, cg)], p4);
    }
#pragma unroll
    for (int msk = 1; msk < 16; msk <<= 1)
#pragma unroll
      for (int i = 0; i < 4; ++i) psum[i] += __shfl_xor(psum[i], msk);
#pragma unroll
    for (int i = 0; i < 4; ++i) l[i] += psum[i];
    __syncthreads();

#pragma unroll
    for (int j4 = 0; j4 < 16; ++j4) {
      float4 p4[4], v4[4];
#pragma unroll
      for (int i = 0; i < 4; ++i) p4[i] = ld4(&ps[idxB(rr + i, j4)]);
#pragma unroll
      for (int jj = 0; jj < 4; ++jj) v4[jj] = ld4(&vs[idxA(j4 * 4 + jj, cg)]);
#pragma unroll
      for (int i = 0; i < 4; ++i) {
        acc[i].x += p4[i].x * v4[0].x + p4[i].y * v4[1].x + p4[i].z * v4[2].x + p4[i].w * v4[3].x;
        acc[i].y += p4[i].x * v4[0].y + p4[i].y * v4[1].y + p4[i].z * v4[2].y + p4[i].w * v4[3].y;
        acc[i].z += p4[i].x * v4[0].z + p4[i].y * v4[1].z + p4[i].z * v4[2].z + p4[i].w * v4[3].z;
        acc[i].w += p4[i].x * v4[0].w + p4[i].y * v4[1].w + p4[i].z * v4[2].w + p4[i].w * v4[3].w;
      }
    }
    __syncthreads();
  }
#pragma unroll
  for (int i = 0; i < 4; ++i) {
    float inv = 1.0f / l[i];
    float4 o;
    o.x = acc[i].x * inv; o.y = acc[i].y * inv;
    o.z = acc[i].z * inv; o.w = acc[i].w * inv;
    st4(&O[(size_t)(q0 + rr + i) * HID + h * DHEAD + dd], o);
  }
}

// ---------------- Router (top-2 + softmax over the two) ----------------
__global__ __launch_bounds__(64) void router_kernel(const float* __restrict__ t2,
                                                    const float* __restrict__ rw,
                                                    const float* __restrict__ rb,
                                                    int* __restrict__ cnt,
                                                    int* __restrict__ te,
                                                    float* __restrict__ tw) {
  int t = blockIdx.x;
  int lane = threadIdx.x;
  int e = lane >> 3, p = lane & 7;
  const float4* x4 = (const float4*)(t2 + (size_t)t * HID);
  const float4* w4 = (const float4*)(rw + (size_t)e * HID);
  float s = 0.f;
  for (int i = 0; i < 64; ++i) {
    float4 xv = x4[p + 8 * i];
    float4 wv = w4[p + 8 * i];
    s += xv.x * wv.x + xv.y * wv.y + xv.z * wv.z + xv.w * wv.w;
  }
  s += __shfl_xor(s, 1);
  s += __shfl_xor(s, 2);
  s += __shfl_xor(s, 4);
  float logit = s + rb[e];
  float lg[8];
#pragma unroll
  for (int e2 = 0; e2 < 8; ++e2) lg[e2] = __shfl(logit, e2 * 8);
  if (lane == 0) {
    int b0 = 0; float v0 = lg[0];
#pragma unroll
    for (int e2 = 1; e2 < 8; ++e2)
      if (lg[e2] > v0) { v0 = lg[e2]; b0 = e2; }
    int b1 = -1; float v1 = -3.0e38f;
#pragma unroll
    for (int e2 = 0; e2 < 8; ++e2)
      if (e2 != b0 && lg[e2] > v1) { v1 = lg[e2]; b1 = e2; }
    float e1 = __expf(v1 - v0);
    float z = 1.0f + e1;
    te[2 * t] = b0; te[2 * t + 1] = b1;
    tw[2 * t] = 1.0f / z; tw[2 * t + 1] = e1 / z;
    atomicAdd(&cnt[b0], 1);
    atomicAdd(&cnt[b1], 1);
  }
}

__global__ void zero_cnt_kernel(int* __restrict__ cnt) {
  if (threadIdx.x < 8) cnt[threadIdx.x] = 0;
}

__global__ void offsets_kernel(const int* __restrict__ cnt, int* __restrict__ offE,
                               int* __restrict__ fill) {
  if (threadIdx.x == 0) {
    int r = 0;
    for (int e = 0; e < 8; ++e) { offE[e] = r; fill[e] = r; r += cnt[e]; }
  }
}

__global__ __launch_bounds__(256) void scatter_kernel(const int* __restrict__ te,
                                                      int* __restrict__ fill,
                                                      int* __restrict__ tokbuf,
                                                      int* __restrict__ tokslot) {
  int t = blockIdx.x * 256 + threadIdx.x;
  if (t < SEQ) {
    for (int j = 0; j < 2; ++j) {
      int e = te[2 * t + j];
      int slot = atomicAdd(&fill[e], 1);
      tokbuf[slot] = t;
      tokslot[2 * t + j] = slot;
    }
  }
}

// ---------------- final combine: out = x2 + w0*down[s0] + w1*down[s1] ----------------
__global__ __launch_bounds__(256) void combine_kernel(const float* __restrict__ x2,
                                                      const float* __restrict__ dout,
                                                      const int* __restrict__ tokslot,
                                                      const float* __restrict__ tw,
                                                      float* __restrict__ out) {
  int idx = blockIdx.x * 256 + threadIdx.x;
  int t = idx >> 9, c = idx & 511;
  int s0 = tokslot[2 * t], s1 = tokslot[2 * t + 1];
  float w0 = tw[2 * t], w1 = tw[2 * t + 1];
  float4 r = ld4(x2 + (size_t)t * HID + c * 4);
  float4 a = ld4(dout + (size_t)s0 * HID + c * 4);
  float4 b = ld4(dout + (size_t)s1 * HID + c * 4);
  float4 o;
  o.x = r.x + w0 * a.x + w1 * b.x;
  o.y = r.y + w0 * a.y + w1 * b.y;
  o.z = r.z + w0 * a.z + w1 * b.z;
  o.w = r.w + w0 * a.w + w1 * b.w;
  st4(out + (size_t)t * HID + c * 4, o);
}

// ---------------- launch ----------------
extern "C" void kernel_launch(void* const* d_in, const int* in_sizes, int n_in,
                              void* d_out, int out_size, void* d_ws, size_t ws_size,
                              hipStream_t stream) {
  (void)in_sizes; (void)n_in; (void)out_size; (void)ws_size;
  const float* x      = (const float*)d_in[0];
  // d_in[1] = attention_mask (unused; reproduced analytically)
  const float* cosT   = (const float*)d_in[2];
  const float* sinT   = (const float*)d_in[3];
  const float* wq     = (const float*)d_in[4];
  const float* bq     = (const float*)d_in[5];
  const float* wk     = (const float*)d_in[6];
  const float* bk     = (const float*)d_in[7];
  const float* wv     = (const float*)d_in[8];
  const float* bv     = (const float*)d_in[9];
  const float* wo     = (const float*)d_in[10];
  const float* bo     = (const float*)d_in[11];
  const float* sinks  = (const float*)d_in[12];
  const float* ln1w   = (const float*)d_in[13];
  const float* ln2w   = (const float*)d_in[14];
  const float* rw     = (const float*)d_in[15];
  const float* rb     = (const float*)d_in[16];
  const float* guw    = (const float*)d_in[17];
  const float* gub    = (const float*)d_in[18];
  const float* dww    = (const float*)d_in[19];
  const float* dwb    = (const float*)d_in[20];
  float* out = (float*)d_out;

  float* ws = (float*)d_ws;
  const size_t T2M = 2097152;  // 2M floats = one (1024,2048) tensor
  float* h    = ws;             // [0, 2M)   — dead after QKV
  float* q    = ws + 1 * T2M;   // [2M, 4M)
  float* k    = ws + 2 * T2M;   // [4M, 6M)
  float* v    = ws + 3 * T2M;   // [6M, 8M)
  float* attn = ws;             // alias h
  float* x2   = ws + 4 * T2M;   // [8M, 10M)
  float* t2   = ws + 5 * T2M;   // [10M, 12M)
  float* actb = ws + 1 * T2M;   // [2M, 6M)  — aliases q,k (dead after attention)
  float* down = ws + 6 * T2M;   // [12M, 16M)
  int* misc = (int*)(ws + 3 * T2M);  // inside v region — written only after attention
  int* cnt     = misc;
  int* offE    = misc + 8;
  int* fill    = misc + 16;
  int* te      = misc + 32;
  int* tokslot = misc + 32 + 2048;
  int* tokbuf  = misc + 32 + 4096;
  float* tw    = (float*)(misc + 32 + 6144);

  rmsnorm_kernel<<<SEQ, 256, 0, stream>>>(x, ln1w, h);
  qkv_bf16_kernel<<<dim3(16, 8, 3), 256, 0, stream>>>(h, wq, wk, wv, bq, bk, bv, q, k, v);
  rope_kernel<<<4096, 256, 0, stream>>>(q, k, cosT, sinT);
  attn_kernel<<<dim3(16, 32), 256, 0, stream>>>(q, k, v, sinks, attn);
  wo_bf16_kernel<<<dim3(16, 8), 256, 0, stream>>>(attn, wo, bo, x, x2);
  rmsnorm_kernel<<<SEQ, 256, 0, stream>>>(x2, ln2w, t2);
  zero_cnt_kernel<<<1, 64, 0, stream>>>(cnt);
  router_kernel<<<SEQ, 64, 0, stream>>>(t2, rw, rb, cnt, te, tw);
  offsets_kernel<<<1, 64, 0, stream>>>(cnt, offE, fill);
  scatter_kernel<<<4, 256, 0, stream>>>(te, fill, tokbuf, tokslot);
  gateup_bf16_kernel<<<dim3(32, 8, 8), 256, 0, stream>>>(t2, guw, gub, tokbuf, cnt, offE, actb);
  down_bf16_kernel<<<dim3(16, 8, 8), 256, 0, stream>>>(actb, dww, dwb, cnt, offE, down);
  combine_kernel<<<2048, 256, 0, stream>>>(x2, down, tokslot, tw, out);
}